// Round 1
// baseline (258.424 us; speedup 1.0000x reference)
//
#include <hip/hip_runtime.h>
#include <stdint.h>

// GNN block: GCNConv(x@W, sym-norm agg w/ self loops) -> ReLU -> BatchNorm(train) -> JAX dropout
// Stages: GEMM -> degree count -> scan (CSR row_ptr) -> CSR fill -> gather-aggregate
//         -> BN stats -> BN+dropout finalize.
// Dropout mask: JAX threefry2x32, partitionable path (bits = out0 ^ out1), key=(0,42).

#define NN 50000
#define NE 800000
#define DD 128
#define SCAN_B 256
#define NSB ((NN + SCAN_B - 1) / SCAN_B)   // 196

// ---------------- threefry2x32 (JAX-compatible) ----------------
__device__ __forceinline__ uint32_t rotl32(uint32_t x, uint32_t d) {
  return (x << d) | (x >> (32u - d));
}

// bits for flat element j: partitionable path, counts=(0, j), key=(0,42), out0^out1
__device__ __forceinline__ uint32_t threefry_bits(uint32_t idx) {
  const uint32_t ks0 = 0u;
  const uint32_t ks1 = 42u;
  const uint32_t ks2 = 0x1BD11BDAu ^ ks0 ^ ks1;
  uint32_t x0 = ks0;        // counts_hi (0) + ks0
  uint32_t x1 = idx + ks1;  // counts_lo + ks1
#define TF_R(r) { x0 += x1; x1 = rotl32(x1, (r)); x1 ^= x0; }
  TF_R(13u) TF_R(15u) TF_R(26u) TF_R(6u)
  x0 += ks1; x1 += ks2 + 1u;
  TF_R(17u) TF_R(29u) TF_R(16u) TF_R(24u)
  x0 += ks2; x1 += ks0 + 2u;
  TF_R(13u) TF_R(15u) TF_R(26u) TF_R(6u)
  x0 += ks0; x1 += ks1 + 3u;
  TF_R(17u) TF_R(29u) TF_R(16u) TF_R(24u)
  x0 += ks1; x1 += ks2 + 4u;
  TF_R(13u) TF_R(15u) TF_R(26u) TF_R(6u)
  x0 += ks2; x1 += ks0 + 5u;
#undef TF_R
  return x0 ^ x1;
}

// ---------------- GEMM: h[N][128] = x[N][128] @ W[128][128] ----------------
#define BM 128
#define BK 32
__global__ __launch_bounds__(256) void k_gemm(const float* __restrict__ x,
                                              const float* __restrict__ Wm,
                                              float* __restrict__ h) {
  __shared__ float xs[BM][BK + 1];   // padded: stride 33 avoids bank conflicts
  __shared__ float wsh[BK][DD];
  const int t = threadIdx.x;
  const int row0 = blockIdx.x * BM;
  const int tx = t & 15, ty = t >> 4;
  const int c0 = tx * 8, r0 = ty * 8;
  float acc[8][8] = {};

  for (int kc = 0; kc < DD; kc += BK) {
    // stage x tile [128][32] (4096 f32, 16/thread as float4)
#pragma unroll
    for (int q = 0; q < 4; ++q) {
      int s = t + q * 256;          // float4 slot 0..1023
      int r = s >> 3;               // 8 float4 per row
      int kq = s & 7;
      int grow = row0 + r;
      float4 v = make_float4(0.f, 0.f, 0.f, 0.f);
      if (grow < NN)
        v = *reinterpret_cast<const float4*>(&x[(size_t)grow * DD + kc + kq * 4]);
      xs[r][kq * 4 + 0] = v.x;
      xs[r][kq * 4 + 1] = v.y;
      xs[r][kq * 4 + 2] = v.z;
      xs[r][kq * 4 + 3] = v.w;
    }
    // stage W tile [32][128]
#pragma unroll
    for (int q = 0; q < 4; ++q) {
      int s = t + q * 256;
      int kr = s >> 5;              // 32 float4 per W row
      int cq = s & 31;
      float4 v = *reinterpret_cast<const float4*>(&Wm[(size_t)(kc + kr) * DD + cq * 4]);
      *reinterpret_cast<float4*>(&wsh[kr][cq * 4]) = v;
    }
    __syncthreads();
#pragma unroll
    for (int kk = 0; kk < BK; ++kk) {
      float a[8];
#pragma unroll
      for (int i = 0; i < 8; ++i) a[i] = xs[r0 + i][kk];
      float4 wv0 = *reinterpret_cast<const float4*>(&wsh[kk][c0]);
      float4 wv1 = *reinterpret_cast<const float4*>(&wsh[kk][c0 + 4]);
      float w[8] = {wv0.x, wv0.y, wv0.z, wv0.w, wv1.x, wv1.y, wv1.z, wv1.w};
#pragma unroll
      for (int i = 0; i < 8; ++i)
#pragma unroll
        for (int j = 0; j < 8; ++j)
          acc[i][j] = fmaf(a[i], w[j], acc[i][j]);
    }
    __syncthreads();
  }
#pragma unroll
  for (int i = 0; i < 8; ++i) {
    int grow = row0 + r0 + i;
    if (grow < NN) {
      float4* dst = reinterpret_cast<float4*>(&h[(size_t)grow * DD + c0]);
      dst[0] = make_float4(acc[i][0], acc[i][1], acc[i][2], acc[i][3]);
      dst[1] = make_float4(acc[i][4], acc[i][5], acc[i][6], acc[i][7]);
    }
  }
}

// ---------------- degree count (in-degree over dst) ----------------
__global__ void k_count(const int* __restrict__ ei, int* __restrict__ cnt) {
  int e = blockIdx.x * blockDim.x + threadIdx.x;
  if (e < NE) {
    int d = ei[NE + e];
    atomicAdd(&cnt[d], 1);
  }
}

// ---------------- scan stage 1: per-block inclusive scan ----------------
__global__ __launch_bounds__(SCAN_B) void k_scan1(const int* __restrict__ cnt,
                                                  int* __restrict__ tmp,
                                                  int* __restrict__ blk_sums) {
  __shared__ int sm[SCAN_B];
  int t = threadIdx.x;
  int i = blockIdx.x * SCAN_B + t;
  int v = (i < NN) ? cnt[i] : 0;
  sm[t] = v;
  __syncthreads();
  for (int off = 1; off < SCAN_B; off <<= 1) {
    int u = (t >= off) ? sm[t - off] : 0;
    __syncthreads();
    sm[t] += u;
    __syncthreads();
  }
  if (i < NN) tmp[i] = sm[t];
  if (t == SCAN_B - 1) blk_sums[blockIdx.x] = sm[t];
}

// ---------------- scan stage 2: exclusive scan of block sums (1 block) ----------------
__global__ __launch_bounds__(SCAN_B) void k_scan2(const int* __restrict__ blk_sums,
                                                  int* __restrict__ blk_off) {
  __shared__ int sm[SCAN_B];
  int t = threadIdx.x;
  int v = (t < NSB) ? blk_sums[t] : 0;
  sm[t] = v;
  __syncthreads();
  for (int off = 1; off < SCAN_B; off <<= 1) {
    int u = (t >= off) ? sm[t - off] : 0;
    __syncthreads();
    sm[t] += u;
    __syncthreads();
  }
  if (t < NSB) blk_off[t] = sm[t] - v;   // exclusive
}

// ---------------- scan stage 3: row_ptr + dinv ----------------
__global__ void k_scan3(const int* __restrict__ tmp, const int* __restrict__ blk_off,
                        const int* __restrict__ cnt, int* __restrict__ row_ptr,
                        float* __restrict__ dinv) {
  int i = blockIdx.x * SCAN_B + threadIdx.x;
  if (i < NN) {
    row_ptr[i + 1] = tmp[i] + blk_off[i >> 8];
    if (i == 0) row_ptr[0] = 0;
    dinv[i] = rsqrtf((float)cnt[i] + 1.0f);   // deg = in-edges + self loop
  }
}

// ---------------- CSR fill ----------------
__global__ void k_fill(const int* __restrict__ ei, const int* __restrict__ row_ptr,
                       int* __restrict__ cursor, int* __restrict__ colv) {
  int e = blockIdx.x * blockDim.x + threadIdx.x;
  if (e < NE) {
    int s = ei[e];
    int d = ei[NE + e];
    int p = atomicAdd(&cursor[d], 1);
    colv[row_ptr[d] + p] = s;
  }
}

// ---------------- aggregate: one wave per node, lane = 2 channels ----------------
__global__ __launch_bounds__(256) void k_agg(const float* __restrict__ h,
                                             const int* __restrict__ row_ptr,
                                             const int* __restrict__ colv,
                                             const float* __restrict__ dinv,
                                             const float* __restrict__ bias,
                                             float* __restrict__ z) {
  int wave = threadIdx.x >> 6;
  int lane = threadIdx.x & 63;
  int node = blockIdx.x * 4 + wave;
  if (node >= NN) return;
  const float2* hv = reinterpret_cast<const float2*>(h);
  float di = dinv[node];
  float2 hs = hv[(size_t)node * 64 + lane];
  float w0 = di * di;                       // self-loop norm
  float ax = hs.x * w0, ay = hs.y * w0;
  int beg = row_ptr[node], end = row_ptr[node + 1];
  for (int e = beg; e < end; ++e) {
    int s = colv[e];
    float wgt = dinv[s] * di;
    float2 hm = hv[(size_t)s * 64 + lane];
    ax = fmaf(hm.x, wgt, ax);
    ay = fmaf(hm.y, wgt, ay);
  }
  float2 bb = reinterpret_cast<const float2*>(bias)[lane];
  float zx = fmaxf(ax + bb.x, 0.f);
  float zy = fmaxf(ay + bb.y, 0.f);
  reinterpret_cast<float2*>(z)[(size_t)node * 64 + lane] = make_float2(zx, zy);
}

// ---------------- BN stats: per-channel sum / sumsq ----------------
__global__ __launch_bounds__(256) void k_stats(const float* __restrict__ z,
                                               float* __restrict__ bn_sum,
                                               float* __restrict__ bn_sumsq) {
  int t = threadIdx.x;
  int c = t & 127;
  int half = t >> 7;    // 0/1: two rows in flight per block
  float s = 0.f, s2 = 0.f;
  for (int r = blockIdx.x * 2 + half; r < NN; r += gridDim.x * 2) {
    float v = z[(size_t)r * DD + c];
    s += v;
    s2 = fmaf(v, v, s2);
  }
  __shared__ float sm[256], sm2[256];
  sm[t] = s; sm2[t] = s2;
  __syncthreads();
  if (t < 128) {
    atomicAdd(&bn_sum[c], sm[t] + sm[t + 128]);
    atomicAdd(&bn_sumsq[c], sm2[t] + sm2[t + 128]);
  }
}

// ---------------- finalize: BN + dropout, in place on d_out ----------------
__global__ __launch_bounds__(256) void k_final(float* __restrict__ z,
                                               const float* __restrict__ bn_sum,
                                               const float* __restrict__ bn_sumsq,
                                               const float* __restrict__ gamma,
                                               const float* __restrict__ beta) {
  int j = blockIdx.x * blockDim.x + threadIdx.x;
  if (j >= NN * DD) return;
  int c = j & 127;
  const float invN = 1.0f / (float)NN;
  float mean = bn_sum[c] * invN;
  float var = bn_sumsq[c] * invN - mean * mean;
  float rs = rsqrtf(var + 1e-5f);
  float val = (z[j] - mean) * rs * gamma[c] + beta[c];
  uint32_t bits = threefry_bits((uint32_t)j);
  float u = __uint_as_float((bits >> 9) | 0x3f800000u) - 1.0f;
  z[j] = (u < 0.9f) ? val * (1.0f / 0.9f) : 0.0f;
}

// ---------------- launch ----------------
extern "C" void kernel_launch(void* const* d_in, const int* in_sizes, int n_in,
                              void* d_out, int out_size, void* d_ws, size_t ws_size,
                              hipStream_t stream) {
  const float* x     = (const float*)d_in[0];
  const int*   ei    = (const int*)d_in[1];    // edge_index [2][E] int32
  const float* Wm    = (const float*)d_in[2];
  const float* bvec  = (const float*)d_in[3];
  const float* gamma = (const float*)d_in[4];
  const float* beta  = (const float*)d_in[5];
  float* zout = (float*)d_out;

  // workspace layout
  float* hbuf    = (float*)d_ws;                       // NN*DD
  int* colv      = (int*)(hbuf + (size_t)NN * DD);     // NE
  int* cnt       = colv + NE;                          // NN
  int* cursor    = cnt + NN;                           // NN
  float* bn_sum  = (float*)(cursor + NN);              // DD
  float* bn_sumsq= bn_sum + DD;                        // DD
  int* tmp_scan  = (int*)(bn_sumsq + DD);              // NN
  int* row_ptr   = tmp_scan + NN;                      // NN+1
  float* dinv    = (float*)(row_ptr + NN + 1);         // NN
  int* blk_sums  = (int*)(dinv + NN);                  // NSB
  int* blk_off   = blk_sums + NSB;                     // NSB

  // zero the accumulators (cnt, cursor, bn_sum, bn_sumsq are contiguous)
  hipMemsetAsync(cnt, 0, (size_t)(2 * NN + 2 * DD) * sizeof(int), stream);

  k_gemm<<<(NN + BM - 1) / BM, 256, 0, stream>>>(x, Wm, hbuf);
  k_count<<<(NE + 255) / 256, 256, 0, stream>>>(ei, cnt);
  k_scan1<<<NSB, SCAN_B, 0, stream>>>(cnt, tmp_scan, blk_sums);
  k_scan2<<<1, SCAN_B, 0, stream>>>(blk_sums, blk_off);
  k_scan3<<<NSB, SCAN_B, 0, stream>>>(tmp_scan, blk_off, cnt, row_ptr, dinv);
  k_fill<<<(NE + 255) / 256, 256, 0, stream>>>(ei, row_ptr, cursor, colv);
  k_agg<<<(NN + 3) / 4, 256, 0, stream>>>(hbuf, row_ptr, colv, dinv, bvec, zout);
  k_stats<<<400, 256, 0, stream>>>(zout, bn_sum, bn_sumsq);
  k_final<<<(NN * DD + 255) / 256, 256, 0, stream>>>(zout, bn_sum, bn_sumsq, gamma, beta);
}

// Round 2
// 211.457 us; speedup vs baseline: 1.2221x; 1.2221x over previous
//
#include <hip/hip_runtime.h>
#include <stdint.h>

// GNN block: GCNConv(x@W, sym-norm agg w/ self loops) -> ReLU -> BatchNorm(train) -> JAX dropout
// R2 changes: h stored as bf16 (halves gather bytes), per-edge norm precomputed in CSR fill
// (kills the colv->dinv dependent hop), 8-wide unrolled gather loop for MLP.

#define NN 50000
#define NE 800000
#define DD 128
#define SCAN_B 256
#define NSB ((NN + SCAN_B - 1) / SCAN_B)   // 196

// ---------------- threefry2x32 (JAX-compatible) ----------------
__device__ __forceinline__ uint32_t rotl32(uint32_t x, uint32_t d) {
  return (x << d) | (x >> (32u - d));
}

__device__ __forceinline__ uint32_t threefry_bits(uint32_t idx) {
  const uint32_t ks0 = 0u;
  const uint32_t ks1 = 42u;
  const uint32_t ks2 = 0x1BD11BDAu ^ ks0 ^ ks1;
  uint32_t x0 = ks0;        // counts_hi (0) + ks0
  uint32_t x1 = idx + ks1;  // counts_lo + ks1
#define TF_R(r) { x0 += x1; x1 = rotl32(x1, (r)); x1 ^= x0; }
  TF_R(13u) TF_R(15u) TF_R(26u) TF_R(6u)
  x0 += ks1; x1 += ks2 + 1u;
  TF_R(17u) TF_R(29u) TF_R(16u) TF_R(24u)
  x0 += ks2; x1 += ks0 + 2u;
  TF_R(13u) TF_R(15u) TF_R(26u) TF_R(6u)
  x0 += ks0; x1 += ks1 + 3u;
  TF_R(17u) TF_R(29u) TF_R(16u) TF_R(24u)
  x0 += ks1; x1 += ks2 + 4u;
  TF_R(13u) TF_R(15u) TF_R(26u) TF_R(6u)
  x0 += ks2; x1 += ks0 + 5u;
#undef TF_R
  return x0 ^ x1;
}

__device__ __forceinline__ uint32_t f2bf(float f) {
  uint32_t u = __float_as_uint(f);
  return (u + 0x7fffu + ((u >> 16) & 1u)) >> 16;   // RNE
}
__device__ __forceinline__ float bf_lo(uint32_t p) { return __uint_as_float(p << 16); }
__device__ __forceinline__ float bf_hi(uint32_t p) { return __uint_as_float(p & 0xffff0000u); }

// ---------------- GEMM: hbf[N][128](bf16) = x[N][128] @ W[128][128] ----------------
#define BM 128
#define BK 32
__global__ __launch_bounds__(256) void k_gemm(const float* __restrict__ x,
                                              const float* __restrict__ Wm,
                                              uint16_t* __restrict__ hbf) {
  __shared__ float xs[BM][BK + 1];
  __shared__ float wsh[BK][DD];
  const int t = threadIdx.x;
  const int row0 = blockIdx.x * BM;
  const int tx = t & 15, ty = t >> 4;
  const int c0 = tx * 8, r0 = ty * 8;
  float acc[8][8] = {};

  for (int kc = 0; kc < DD; kc += BK) {
#pragma unroll
    for (int q = 0; q < 4; ++q) {
      int s = t + q * 256;
      int r = s >> 3;
      int kq = s & 7;
      int grow = row0 + r;
      float4 v = make_float4(0.f, 0.f, 0.f, 0.f);
      if (grow < NN)
        v = *reinterpret_cast<const float4*>(&x[(size_t)grow * DD + kc + kq * 4]);
      xs[r][kq * 4 + 0] = v.x;
      xs[r][kq * 4 + 1] = v.y;
      xs[r][kq * 4 + 2] = v.z;
      xs[r][kq * 4 + 3] = v.w;
    }
#pragma unroll
    for (int q = 0; q < 4; ++q) {
      int s = t + q * 256;
      int kr = s >> 5;
      int cq = s & 31;
      float4 v = *reinterpret_cast<const float4*>(&Wm[(size_t)(kc + kr) * DD + cq * 4]);
      *reinterpret_cast<float4*>(&wsh[kr][cq * 4]) = v;
    }
    __syncthreads();
#pragma unroll
    for (int kk = 0; kk < BK; ++kk) {
      float a[8];
#pragma unroll
      for (int i = 0; i < 8; ++i) a[i] = xs[r0 + i][kk];
      float4 wv0 = *reinterpret_cast<const float4*>(&wsh[kk][c0]);
      float4 wv1 = *reinterpret_cast<const float4*>(&wsh[kk][c0 + 4]);
      float w[8] = {wv0.x, wv0.y, wv0.z, wv0.w, wv1.x, wv1.y, wv1.z, wv1.w};
#pragma unroll
      for (int i = 0; i < 8; ++i)
#pragma unroll
        for (int j = 0; j < 8; ++j)
          acc[i][j] = fmaf(a[i], w[j], acc[i][j]);
    }
    __syncthreads();
  }
#pragma unroll
  for (int i = 0; i < 8; ++i) {
    int grow = row0 + r0 + i;
    if (grow < NN) {
      uint32_t p0 = f2bf(acc[i][0]) | (f2bf(acc[i][1]) << 16);
      uint32_t p1 = f2bf(acc[i][2]) | (f2bf(acc[i][3]) << 16);
      uint32_t p2 = f2bf(acc[i][4]) | (f2bf(acc[i][5]) << 16);
      uint32_t p3 = f2bf(acc[i][6]) | (f2bf(acc[i][7]) << 16);
      *reinterpret_cast<uint4*>(&hbf[(size_t)grow * DD + c0]) = make_uint4(p0, p1, p2, p3);
    }
  }
}

// ---------------- degree count (in-degree over dst) ----------------
__global__ void k_count(const int* __restrict__ ei, int* __restrict__ cnt) {
  int e = blockIdx.x * blockDim.x + threadIdx.x;
  if (e < NE) atomicAdd(&cnt[ei[NE + e]], 1);
}

// ---------------- scan stage 1 ----------------
__global__ __launch_bounds__(SCAN_B) void k_scan1(const int* __restrict__ cnt,
                                                  int* __restrict__ tmp,
                                                  int* __restrict__ blk_sums) {
  __shared__ int sm[SCAN_B];
  int t = threadIdx.x;
  int i = blockIdx.x * SCAN_B + t;
  int v = (i < NN) ? cnt[i] : 0;
  sm[t] = v;
  __syncthreads();
  for (int off = 1; off < SCAN_B; off <<= 1) {
    int u = (t >= off) ? sm[t - off] : 0;
    __syncthreads();
    sm[t] += u;
    __syncthreads();
  }
  if (i < NN) tmp[i] = sm[t];
  if (t == SCAN_B - 1) blk_sums[blockIdx.x] = sm[t];
}

// ---------------- scan stage 2 ----------------
__global__ __launch_bounds__(SCAN_B) void k_scan2(const int* __restrict__ blk_sums,
                                                  int* __restrict__ blk_off) {
  __shared__ int sm[SCAN_B];
  int t = threadIdx.x;
  int v = (t < NSB) ? blk_sums[t] : 0;
  sm[t] = v;
  __syncthreads();
  for (int off = 1; off < SCAN_B; off <<= 1) {
    int u = (t >= off) ? sm[t - off] : 0;
    __syncthreads();
    sm[t] += u;
    __syncthreads();
  }
  if (t < NSB) blk_off[t] = sm[t] - v;
}

// ---------------- scan stage 3: row_ptr + dinv ----------------
__global__ void k_scan3(const int* __restrict__ tmp, const int* __restrict__ blk_off,
                        const int* __restrict__ cnt, int* __restrict__ row_ptr,
                        float* __restrict__ dinv) {
  int i = blockIdx.x * SCAN_B + threadIdx.x;
  if (i < NN) {
    row_ptr[i + 1] = tmp[i] + blk_off[i >> 8];
    if (i == 0) row_ptr[0] = 0;
    dinv[i] = rsqrtf((float)cnt[i] + 1.0f);
  }
}

// ---------------- CSR fill: col + precomputed edge norm ----------------
__global__ void k_fill(const int* __restrict__ ei, const int* __restrict__ row_ptr,
                       const float* __restrict__ dinv, int* __restrict__ cursor,
                       int* __restrict__ colv, float* __restrict__ wn) {
  int e = blockIdx.x * blockDim.x + threadIdx.x;
  if (e < NE) {
    int s = ei[e];
    int d = ei[NE + e];
    int p = atomicAdd(&cursor[d], 1);
    int idx = row_ptr[d] + p;
    colv[idx] = s;
    wn[idx] = dinv[s] * dinv[d];
  }
}

// ---------------- aggregate: one wave per node, lane = 2 bf16 channels ----------------
__global__ __launch_bounds__(256) void k_agg(const uint16_t* __restrict__ hbf,
                                             const int* __restrict__ row_ptr,
                                             const int* __restrict__ colv,
                                             const float* __restrict__ wn,
                                             const float* __restrict__ dinv,
                                             const float* __restrict__ bias,
                                             float* __restrict__ z) {
  int wave = threadIdx.x >> 6;
  int lane = threadIdx.x & 63;
  int node = blockIdx.x * 4 + wave;
  if (node >= NN) return;
  const uint32_t* hp = reinterpret_cast<const uint32_t*>(hbf);

  float di = dinv[node];
  float w0 = di * di;
  uint32_t ms = hp[(size_t)node * 64 + lane];
  float ax = bf_lo(ms) * w0, ay = bf_hi(ms) * w0;

  int e = row_ptr[node], end = row_ptr[node + 1];
  while (e + 8 <= end) {
    int s[8]; float w[8]; uint32_t m[8];
#pragma unroll
    for (int q = 0; q < 8; ++q) { s[q] = colv[e + q]; w[q] = wn[e + q]; }
#pragma unroll
    for (int q = 0; q < 8; ++q) m[q] = hp[(size_t)s[q] * 64 + lane];
#pragma unroll
    for (int q = 0; q < 8; ++q) {
      ax = fmaf(bf_lo(m[q]), w[q], ax);
      ay = fmaf(bf_hi(m[q]), w[q], ay);
    }
    e += 8;
  }
  while (e < end) {
    int s0 = colv[e]; float wq = wn[e];
    uint32_t m0 = hp[(size_t)s0 * 64 + lane];
    ax = fmaf(bf_lo(m0), wq, ax);
    ay = fmaf(bf_hi(m0), wq, ay);
    ++e;
  }
  float2 bb = reinterpret_cast<const float2*>(bias)[lane];
  float zx = fmaxf(ax + bb.x, 0.f);
  float zy = fmaxf(ay + bb.y, 0.f);
  reinterpret_cast<float2*>(z)[(size_t)node * 64 + lane] = make_float2(zx, zy);
}

// ---------------- BN stats ----------------
__global__ __launch_bounds__(256) void k_stats(const float* __restrict__ z,
                                               float* __restrict__ bn_sum,
                                               float* __restrict__ bn_sumsq) {
  int t = threadIdx.x;
  int c = t & 127;
  int half = t >> 7;
  float s = 0.f, s2 = 0.f;
  for (int r = blockIdx.x * 2 + half; r < NN; r += gridDim.x * 2) {
    float v = z[(size_t)r * DD + c];
    s += v;
    s2 = fmaf(v, v, s2);
  }
  __shared__ float sm[256], sm2[256];
  sm[t] = s; sm2[t] = s2;
  __syncthreads();
  if (t < 128) {
    atomicAdd(&bn_sum[c], sm[t] + sm[t + 128]);
    atomicAdd(&bn_sumsq[c], sm2[t] + sm2[t + 128]);
  }
}

// ---------------- finalize: BN + dropout ----------------
__global__ __launch_bounds__(256) void k_final(float* __restrict__ z,
                                               const float* __restrict__ bn_sum,
                                               const float* __restrict__ bn_sumsq,
                                               const float* __restrict__ gamma,
                                               const float* __restrict__ beta) {
  int j = blockIdx.x * blockDim.x + threadIdx.x;
  if (j >= NN * DD) return;
  int c = j & 127;
  const float invN = 1.0f / (float)NN;
  float mean = bn_sum[c] * invN;
  float var = bn_sumsq[c] * invN - mean * mean;
  float rs = rsqrtf(var + 1e-5f);
  float val = (z[j] - mean) * rs * gamma[c] + beta[c];
  uint32_t bits = threefry_bits((uint32_t)j);
  float u = __uint_as_float((bits >> 9) | 0x3f800000u) - 1.0f;
  z[j] = (u < 0.9f) ? val * (1.0f / 0.9f) : 0.0f;
}

// ---------------- launch ----------------
extern "C" void kernel_launch(void* const* d_in, const int* in_sizes, int n_in,
                              void* d_out, int out_size, void* d_ws, size_t ws_size,
                              hipStream_t stream) {
  const float* x     = (const float*)d_in[0];
  const int*   ei    = (const int*)d_in[1];
  const float* Wm    = (const float*)d_in[2];
  const float* bvec  = (const float*)d_in[3];
  const float* gamma = (const float*)d_in[4];
  const float* beta  = (const float*)d_in[5];
  float* zout = (float*)d_out;

  // workspace layout (4B units)
  uint16_t* hbf  = (uint16_t*)d_ws;                         // NN*DD bf16
  int* colv      = (int*)(hbf + (size_t)NN * DD);           // NE
  float* wn      = (float*)(colv + NE);                     // NE
  int* cnt       = (int*)(wn + NE);                         // NN
  int* cursor    = cnt + NN;                                // NN
  float* bn_sum  = (float*)(cursor + NN);                   // DD
  float* bn_sumsq= bn_sum + DD;                             // DD
  int* tmp_scan  = (int*)(bn_sumsq + DD);                   // NN
  int* row_ptr   = tmp_scan + NN;                           // NN+1
  float* dinv    = (float*)(row_ptr + NN + 1);              // NN
  int* blk_sums  = (int*)(dinv + NN);                       // NSB
  int* blk_off   = blk_sums + NSB;                          // NSB

  hipMemsetAsync(cnt, 0, (size_t)(2 * NN + 2 * DD) * sizeof(int), stream);

  k_gemm<<<(NN + BM - 1) / BM, 256, 0, stream>>>(x, Wm, hbf);
  k_count<<<(NE + 255) / 256, 256, 0, stream>>>(ei, cnt);
  k_scan1<<<NSB, SCAN_B, 0, stream>>>(cnt, tmp_scan, blk_sums);
  k_scan2<<<1, SCAN_B, 0, stream>>>(blk_sums, blk_off);
  k_scan3<<<NSB, SCAN_B, 0, stream>>>(tmp_scan, blk_off, cnt, row_ptr, dinv);
  k_fill<<<(NE + 255) / 256, 256, 0, stream>>>(ei, row_ptr, dinv, cursor, colv, wn);
  k_agg<<<(NN + 3) / 4, 256, 0, stream>>>(hbf, row_ptr, colv, wn, dinv, bvec, zout);
  k_stats<<<400, 256, 0, stream>>>(zout, bn_sum, bn_sumsq);
  k_final<<<(NN * DD + 255) / 256, 256, 0, stream>>>(zout, bn_sum, bn_sumsq, gamma, beta);
}

// Round 3
// 180.241 us; speedup vs baseline: 1.4338x; 1.1732x over previous
//
#include <hip/hip_runtime.h>
#include <stdint.h>

// GNN block: GCNConv(x@W, sym-norm agg w/ self loops) -> ReLU -> BatchNorm(train) -> JAX dropout
// R3 changes: k_fill writes ONLY colv (wn recomputed in k_agg from L2-resident dinv);
// slot assignment fused into k_count via pos[e] so k_fill is atomic-free.

#define NN 50000
#define NE 800000
#define DD 128
#define SCAN_B 256
#define NSB ((NN + SCAN_B - 1) / SCAN_B)   // 196

// ---------------- threefry2x32 (JAX-compatible) ----------------
__device__ __forceinline__ uint32_t rotl32(uint32_t x, uint32_t d) {
  return (x << d) | (x >> (32u - d));
}

__device__ __forceinline__ uint32_t threefry_bits(uint32_t idx) {
  const uint32_t ks0 = 0u;
  const uint32_t ks1 = 42u;
  const uint32_t ks2 = 0x1BD11BDAu ^ ks0 ^ ks1;
  uint32_t x0 = ks0;        // counts_hi (0) + ks0
  uint32_t x1 = idx + ks1;  // counts_lo + ks1
#define TF_R(r) { x0 += x1; x1 = rotl32(x1, (r)); x1 ^= x0; }
  TF_R(13u) TF_R(15u) TF_R(26u) TF_R(6u)
  x0 += ks1; x1 += ks2 + 1u;
  TF_R(17u) TF_R(29u) TF_R(16u) TF_R(24u)
  x0 += ks2; x1 += ks0 + 2u;
  TF_R(13u) TF_R(15u) TF_R(26u) TF_R(6u)
  x0 += ks0; x1 += ks1 + 3u;
  TF_R(17u) TF_R(29u) TF_R(16u) TF_R(24u)
  x0 += ks1; x1 += ks2 + 4u;
  TF_R(13u) TF_R(15u) TF_R(26u) TF_R(6u)
  x0 += ks2; x1 += ks0 + 5u;
#undef TF_R
  return x0 ^ x1;
}

__device__ __forceinline__ uint32_t f2bf(float f) {
  uint32_t u = __float_as_uint(f);
  return (u + 0x7fffu + ((u >> 16) & 1u)) >> 16;   // RNE
}
__device__ __forceinline__ float bf_lo(uint32_t p) { return __uint_as_float(p << 16); }
__device__ __forceinline__ float bf_hi(uint32_t p) { return __uint_as_float(p & 0xffff0000u); }

// ---------------- GEMM: hbf[N][128](bf16) = x[N][128] @ W[128][128] ----------------
#define BM 128
#define BK 32
__global__ __launch_bounds__(256) void k_gemm(const float* __restrict__ x,
                                              const float* __restrict__ Wm,
                                              uint16_t* __restrict__ hbf) {
  __shared__ float xs[BM][BK + 1];
  __shared__ float wsh[BK][DD];
  const int t = threadIdx.x;
  const int row0 = blockIdx.x * BM;
  const int tx = t & 15, ty = t >> 4;
  const int c0 = tx * 8, r0 = ty * 8;
  float acc[8][8] = {};

  for (int kc = 0; kc < DD; kc += BK) {
#pragma unroll
    for (int q = 0; q < 4; ++q) {
      int s = t + q * 256;
      int r = s >> 3;
      int kq = s & 7;
      int grow = row0 + r;
      float4 v = make_float4(0.f, 0.f, 0.f, 0.f);
      if (grow < NN)
        v = *reinterpret_cast<const float4*>(&x[(size_t)grow * DD + kc + kq * 4]);
      xs[r][kq * 4 + 0] = v.x;
      xs[r][kq * 4 + 1] = v.y;
      xs[r][kq * 4 + 2] = v.z;
      xs[r][kq * 4 + 3] = v.w;
    }
#pragma unroll
    for (int q = 0; q < 4; ++q) {
      int s = t + q * 256;
      int kr = s >> 5;
      int cq = s & 31;
      float4 v = *reinterpret_cast<const float4*>(&Wm[(size_t)(kc + kr) * DD + cq * 4]);
      *reinterpret_cast<float4*>(&wsh[kr][cq * 4]) = v;
    }
    __syncthreads();
#pragma unroll
    for (int kk = 0; kk < BK; ++kk) {
      float a[8];
#pragma unroll
      for (int i = 0; i < 8; ++i) a[i] = xs[r0 + i][kk];
      float4 wv0 = *reinterpret_cast<const float4*>(&wsh[kk][c0]);
      float4 wv1 = *reinterpret_cast<const float4*>(&wsh[kk][c0 + 4]);
      float w[8] = {wv0.x, wv0.y, wv0.z, wv0.w, wv1.x, wv1.y, wv1.z, wv1.w};
#pragma unroll
      for (int i = 0; i < 8; ++i)
#pragma unroll
        for (int j = 0; j < 8; ++j)
          acc[i][j] = fmaf(a[i], w[j], acc[i][j]);
    }
    __syncthreads();
  }
#pragma unroll
  for (int i = 0; i < 8; ++i) {
    int grow = row0 + r0 + i;
    if (grow < NN) {
      uint32_t p0 = f2bf(acc[i][0]) | (f2bf(acc[i][1]) << 16);
      uint32_t p1 = f2bf(acc[i][2]) | (f2bf(acc[i][3]) << 16);
      uint32_t p2 = f2bf(acc[i][4]) | (f2bf(acc[i][5]) << 16);
      uint32_t p3 = f2bf(acc[i][6]) | (f2bf(acc[i][7]) << 16);
      *reinterpret_cast<uint4*>(&hbf[(size_t)grow * DD + c0]) = make_uint4(p0, p1, p2, p3);
    }
  }
}

// ---------------- degree count + slot assignment ----------------
__global__ void k_count(const int* __restrict__ ei, int* __restrict__ cnt,
                        int* __restrict__ pos) {
  int e = blockIdx.x * blockDim.x + threadIdx.x;
  if (e < NE) pos[e] = atomicAdd(&cnt[ei[NE + e]], 1);
}

// ---------------- scan stage 1 ----------------
__global__ __launch_bounds__(SCAN_B) void k_scan1(const int* __restrict__ cnt,
                                                  int* __restrict__ tmp,
                                                  int* __restrict__ blk_sums) {
  __shared__ int sm[SCAN_B];
  int t = threadIdx.x;
  int i = blockIdx.x * SCAN_B + t;
  int v = (i < NN) ? cnt[i] : 0;
  sm[t] = v;
  __syncthreads();
  for (int off = 1; off < SCAN_B; off <<= 1) {
    int u = (t >= off) ? sm[t - off] : 0;
    __syncthreads();
    sm[t] += u;
    __syncthreads();
  }
  if (i < NN) tmp[i] = sm[t];
  if (t == SCAN_B - 1) blk_sums[blockIdx.x] = sm[t];
}

// ---------------- scan stage 2 ----------------
__global__ __launch_bounds__(SCAN_B) void k_scan2(const int* __restrict__ blk_sums,
                                                  int* __restrict__ blk_off) {
  __shared__ int sm[SCAN_B];
  int t = threadIdx.x;
  int v = (t < NSB) ? blk_sums[t] : 0;
  sm[t] = v;
  __syncthreads();
  for (int off = 1; off < SCAN_B; off <<= 1) {
    int u = (t >= off) ? sm[t - off] : 0;
    __syncthreads();
    sm[t] += u;
    __syncthreads();
  }
  if (t < NSB) blk_off[t] = sm[t] - v;
}

// ---------------- scan stage 3: row_ptr + dinv ----------------
__global__ void k_scan3(const int* __restrict__ tmp, const int* __restrict__ blk_off,
                        const int* __restrict__ cnt, int* __restrict__ row_ptr,
                        float* __restrict__ dinv) {
  int i = blockIdx.x * SCAN_B + threadIdx.x;
  if (i < NN) {
    row_ptr[i + 1] = tmp[i] + blk_off[i >> 8];
    if (i == 0) row_ptr[0] = 0;
    dinv[i] = rsqrtf((float)cnt[i] + 1.0f);
  }
}

// ---------------- CSR fill: atomic-free, colv only ----------------
__global__ void k_fill(const int* __restrict__ ei, const int* __restrict__ row_ptr,
                       const int* __restrict__ pos, int* __restrict__ colv) {
  int e = blockIdx.x * blockDim.x + threadIdx.x;
  if (e < NE) {
    int d = ei[NE + e];
    colv[row_ptr[d] + pos[e]] = ei[e];
  }
}

// ---------------- aggregate: one wave per node, lane = 2 bf16 channels ----------------
__global__ __launch_bounds__(256) void k_agg(const uint16_t* __restrict__ hbf,
                                             const int* __restrict__ row_ptr,
                                             const int* __restrict__ colv,
                                             const float* __restrict__ dinv,
                                             const float* __restrict__ bias,
                                             float* __restrict__ z) {
  int wave = threadIdx.x >> 6;
  int lane = threadIdx.x & 63;
  int node = blockIdx.x * 4 + wave;
  if (node >= NN) return;
  const uint32_t* hp = reinterpret_cast<const uint32_t*>(hbf);

  float di = dinv[node];
  float w0 = di * di;
  uint32_t ms = hp[(size_t)node * 64 + lane];
  float ax = bf_lo(ms) * w0, ay = bf_hi(ms) * w0;

  int e = row_ptr[node], end = row_ptr[node + 1];
  while (e + 8 <= end) {
    int s[8]; float w[8]; uint32_t m[8];
#pragma unroll
    for (int q = 0; q < 8; ++q) s[q] = colv[e + q];
#pragma unroll
    for (int q = 0; q < 8; ++q) { w[q] = dinv[s[q]]; m[q] = hp[(size_t)s[q] * 64 + lane]; }
#pragma unroll
    for (int q = 0; q < 8; ++q) {
      float wq = w[q] * di;
      ax = fmaf(bf_lo(m[q]), wq, ax);
      ay = fmaf(bf_hi(m[q]), wq, ay);
    }
    e += 8;
  }
  while (e < end) {
    int s0 = colv[e];
    float wq = dinv[s0] * di;
    uint32_t m0 = hp[(size_t)s0 * 64 + lane];
    ax = fmaf(bf_lo(m0), wq, ax);
    ay = fmaf(bf_hi(m0), wq, ay);
    ++e;
  }
  float2 bb = reinterpret_cast<const float2*>(bias)[lane];
  float zx = fmaxf(ax + bb.x, 0.f);
  float zy = fmaxf(ay + bb.y, 0.f);
  reinterpret_cast<float2*>(z)[(size_t)node * 64 + lane] = make_float2(zx, zy);
}

// ---------------- BN stats ----------------
__global__ __launch_bounds__(256) void k_stats(const float* __restrict__ z,
                                               float* __restrict__ bn_sum,
                                               float* __restrict__ bn_sumsq) {
  int t = threadIdx.x;
  int c = t & 127;
  int half = t >> 7;
  float s = 0.f, s2 = 0.f;
  for (int r = blockIdx.x * 2 + half; r < NN; r += gridDim.x * 2) {
    float v = z[(size_t)r * DD + c];
    s += v;
    s2 = fmaf(v, v, s2);
  }
  __shared__ float sm[256], sm2[256];
  sm[t] = s; sm2[t] = s2;
  __syncthreads();
  if (t < 128) {
    atomicAdd(&bn_sum[c], sm[t] + sm[t + 128]);
    atomicAdd(&bn_sumsq[c], sm2[t] + sm2[t + 128]);
  }
}

// ---------------- finalize: BN + dropout ----------------
__global__ __launch_bounds__(256) void k_final(float* __restrict__ z,
                                               const float* __restrict__ bn_sum,
                                               const float* __restrict__ bn_sumsq,
                                               const float* __restrict__ gamma,
                                               const float* __restrict__ beta) {
  int j = blockIdx.x * blockDim.x + threadIdx.x;
  if (j >= NN * DD) return;
  int c = j & 127;
  const float invN = 1.0f / (float)NN;
  float mean = bn_sum[c] * invN;
  float var = bn_sumsq[c] * invN - mean * mean;
  float rs = rsqrtf(var + 1e-5f);
  float val = (z[j] - mean) * rs * gamma[c] + beta[c];
  uint32_t bits = threefry_bits((uint32_t)j);
  float u = __uint_as_float((bits >> 9) | 0x3f800000u) - 1.0f;
  z[j] = (u < 0.9f) ? val * (1.0f / 0.9f) : 0.0f;
}

// ---------------- launch ----------------
extern "C" void kernel_launch(void* const* d_in, const int* in_sizes, int n_in,
                              void* d_out, int out_size, void* d_ws, size_t ws_size,
                              hipStream_t stream) {
  const float* x     = (const float*)d_in[0];
  const int*   ei    = (const int*)d_in[1];
  const float* Wm    = (const float*)d_in[2];
  const float* bvec  = (const float*)d_in[3];
  const float* gamma = (const float*)d_in[4];
  const float* beta  = (const float*)d_in[5];
  float* zout = (float*)d_out;

  // workspace layout (4B units)
  uint16_t* hbf  = (uint16_t*)d_ws;                         // NN*DD bf16
  int* colv      = (int*)(hbf + (size_t)NN * DD);           // NE
  int* pos       = colv + NE;                               // NE
  int* cnt       = pos + NE;                                // NN   (zeroed)
  float* bn_sum  = (float*)(cnt + NN);                      // DD   (zeroed)
  float* bn_sumsq= bn_sum + DD;                             // DD   (zeroed)
  int* tmp_scan  = (int*)(bn_sumsq + DD);                   // NN
  int* row_ptr   = tmp_scan + NN;                           // NN+1
  float* dinv    = (float*)(row_ptr + NN + 1);              // NN
  int* blk_sums  = (int*)(dinv + NN);                       // NSB
  int* blk_off   = blk_sums + NSB;                          // NSB

  hipMemsetAsync(cnt, 0, (size_t)(NN + 2 * DD) * sizeof(int), stream);

  k_gemm<<<(NN + BM - 1) / BM, 256, 0, stream>>>(x, Wm, hbf);
  k_count<<<(NE + 255) / 256, 256, 0, stream>>>(ei, cnt, pos);
  k_scan1<<<NSB, SCAN_B, 0, stream>>>(cnt, tmp_scan, blk_sums);
  k_scan2<<<1, SCAN_B, 0, stream>>>(blk_sums, blk_off);
  k_scan3<<<NSB, SCAN_B, 0, stream>>>(tmp_scan, blk_off, cnt, row_ptr, dinv);
  k_fill<<<(NE + 255) / 256, 256, 0, stream>>>(ei, row_ptr, pos, colv);
  k_agg<<<(NN + 3) / 4, 256, 0, stream>>>(hbf, row_ptr, colv, dinv, bvec, zout);
  k_stats<<<400, 256, 0, stream>>>(zout, bn_sum, bn_sumsq);
  k_final<<<(NN * DD + 255) / 256, 256, 0, stream>>>(zout, bn_sum, bn_sumsq, gamma, beta);
}